// Round 6
// baseline (1068.821 us; speedup 1.0000x reference)
//
#include <hip/hip_runtime.h>
#include <hip/hip_cooperative_groups.h>

namespace cg = cooperative_groups;

// FPS: scan1 (dense full pass) + ONE cooperative kernel for steps 2..9.
// B=64, N=262144, NPOINT=10. Per-chunk state lives in LDS for the whole
// cooperative kernel; steps separated by grid.sync() instead of launch
// boundaries (round-5 showed ~21us per dependent launch).
// Winner slots: per-step u64 atomicMax of (valbits<<32)|(~idx) -> max value,
// lowest index, order-independent => deterministic despite racy LB reads.

#define NPOINT 10
#define NB     64
#define NPTS   262144
#define G      64
#define CH     (NPTS / G)     // 4096
#define TPB    256
#define PPT    (CH / TPB)     // 16
#define BPB    8              // blocks per batch (coop kernel)
#define CPB    8              // chunks per block
#define INIT_DIST 1e10f

// Strict IEEE, reference association order ((dx^2+dy^2)+dz^2), no contraction.
__device__ __forceinline__ float sqdist(float x, float y, float z,
                                        float cx, float cy, float cz) {
    float dx = x - cx, dy = y - cy, dz = z - cz;
    return __fadd_rn(__fadd_rn(__fmul_rn(dx, dx), __fmul_rn(dy, dy)),
                     __fmul_rn(dz, dz));
}

__device__ __forceinline__ unsigned long long packvi(float v, int i) {
    return ((unsigned long long)__float_as_uint(v) << 32) |
           (unsigned)(0xFFFFFFFFu - (unsigned)i);
}
__device__ __forceinline__ int unpack_idx(unsigned long long w) {
    return (int)(0xFFFFFFFFu - (unsigned)(w & 0xFFFFFFFFull));
}

// 64-lane shfl argmax (max val, ties -> lowest idx); result in lane 0.
__device__ __forceinline__ void wave_argmax(float& v, int& i) {
    #pragma unroll
    for (int off = 32; off > 0; off >>= 1) {
        float ov = __shfl_down(v, off); int oi = __shfl_down(i, off);
        if (ov > v || (ov == v && oi < i)) { v = ov; i = oi; }
    }
}

// ---- Kernel A: full scan vs center 0 -> fresh per-chunk (max, argmax).
__global__ __launch_bounds__(TPB) void fps_scan1(
    const float* __restrict__ xyz,
    float* __restrict__ ub, int* __restrict__ uidx)
{
    const int b = blockIdx.y, g = blockIdx.x, tid = threadIdx.x;
    const int lane = tid & 63, wave = tid >> 6;
    const float* xyzb = xyz + (size_t)b * NPTS * 3;
    const float cx = xyzb[0], cy = xyzb[1], cz = xyzb[2];
    __shared__ float s_v[4];
    __shared__ int   s_i[4];

    float bestv = -1.0f; int besti = 0;
    const int p0 = g * CH + tid * PPT;
    #pragma unroll
    for (int grp = 0; grp < PPT / 4; ++grp) {
        const float4* src = (const float4*)(xyzb + (size_t)(p0 + grp * 4) * 3);
        float4 a = src[0], c4 = src[1], e = src[2];
        float px[4] = {a.x, a.w, c4.z, e.y};
        float py[4] = {a.y, c4.x, c4.w, e.z};
        float pz[4] = {a.z, c4.y, e.x, e.w};
        #pragma unroll
        for (int j = 0; j < 4; ++j) {
            float d = fminf(INIT_DIST, sqdist(px[j], py[j], pz[j], cx, cy, cz));
            if (d > bestv) { bestv = d; besti = p0 + grp * 4 + j; }
        }
    }
    wave_argmax(bestv, besti);
    if (lane == 0) { s_v[wave] = bestv; s_i[wave] = besti; }
    __syncthreads();
    if (tid == 0) {
        float v = s_v[0]; int i = s_i[0];
        #pragma unroll
        for (int w = 1; w < 4; ++w) {
            float ov = s_v[w]; int oi = s_i[w];
            if (ov > v || (ov == v && oi < i)) { v = ov; i = oi; }
        }
        ub[b * G + g] = v; uidx[b * G + g] = i;
    }
}

// ---- Kernel B: cooperative, all steps 2..9 + output writes.
__global__ __launch_bounds__(TPB, 2) void fps_steps(
    const float* __restrict__ xyz, int* __restrict__ out,
    const float* __restrict__ ub_g, const int* __restrict__ uidx_g,
    unsigned long long* __restrict__ win)
{
    const int blk = blockIdx.x;
    const int b = blk / BPB, q = blk % BPB;
    const int tid = threadIdx.x;
    const int lane = tid & 63, wave = tid >> 6;
    const float* xyzb = xyz + (size_t)b * NPTS * 3;
    cg::grid_group grid = cg::this_grid();

    __shared__ float scx[NPOINT], scy[NPOINT], scz[NPOINT];
    __shared__ float l_ub[CPB], l_cd[CPB];   // chunk state: stale max, cand
    __shared__ int   l_ui[CPB];              // cand point index
    __shared__ float s_v[4];
    __shared__ int   s_i[4];
    __shared__ float s_lbv;
    __shared__ unsigned long long s_w;

    // init: load per-chunk state, post round-1 winner candidates (exact).
    if (tid < CPB) {
        int c = q * CPB + tid;
        float u = ub_g[b * G + c];
        int   i = uidx_g[b * G + c];
        l_ub[tid] = u; l_cd[tid] = u; l_ui[tid] = i;
        atomicMax(&win[1 * NB + b], packvi(u, i));
    }
    if (tid == 0) { scx[0] = xyzb[0]; scy[0] = xyzb[1]; scz[0] = xyzb[2]; }
    __syncthreads();

    for (int r = 2; r <= NPOINT - 1; ++r) {
        grid.sync();                                  // slot r-1 is final
        if (tid == 0) s_w = atomicMax(&win[(r - 1) * NB + b], 0ULL);
        __syncthreads();
        const int prevIdx = unpack_idx(s_w);
        const size_t po = (size_t)prevIdx * 3;
        const float pcx = xyzb[po], pcy = xyzb[po + 1], pcz = xyzb[po + 2];
        if (tid == 0) { scx[r - 1] = pcx; scy[r - 1] = pcy; scz[r - 1] = pcz; }

        // refresh cands vs new center (stay exact), post as LB/winner cands
        if (tid < CPB) {
            int pi = l_ui[tid];
            size_t qo = (size_t)pi * 3;
            float cd = fminf(l_cd[tid],
                             sqdist(xyzb[qo], xyzb[qo + 1], xyzb[qo + 2],
                                    pcx, pcy, pcz));
            l_cd[tid] = cd;
            atomicMax(&win[r * NB + b], packvi(cd, pi));
        }
        __syncthreads();

        for (int m = 0; m < CPB; ++m) {
            // fresh (monotone-tightening) LB from the winner slot
            if (tid == 0) {
                unsigned long long w = atomicMax(&win[r * NB + b], 0ULL);
                s_lbv = __uint_as_float((unsigned)(w >> 32));
            }
            __syncthreads();
            const bool skip = (l_ub[m] < s_lbv);      // uniform (LDS) decision
            __syncthreads();
            if (skip) continue;

            // exact rescan of chunk m vs centers 0..r-1
            float bestv = -1.0f; int besti = 0;
            const int p0 = (q * CPB + m) * CH + tid * PPT;
            #pragma unroll
            for (int grp = 0; grp < PPT / 4; ++grp) {
                const float4* src = (const float4*)(xyzb + (size_t)(p0 + grp * 4) * 3);
                float4 a = src[0], c4 = src[1], e = src[2];
                float px[4] = {a.x, a.w, c4.z, e.y};
                float py[4] = {a.y, c4.x, c4.w, e.z};
                float pz[4] = {a.z, c4.y, e.x, e.w};
                #pragma unroll
                for (int j = 0; j < 4; ++j) {
                    float dmin = INIT_DIST;
                    for (int k = 0; k < r; ++k)       // runtime bound, LDS bcast
                        dmin = fminf(dmin, sqdist(px[j], py[j], pz[j],
                                                  scx[k], scy[k], scz[k]));
                    if (dmin > bestv) { bestv = dmin; besti = p0 + grp * 4 + j; }
                }
            }
            wave_argmax(bestv, besti);
            if (lane == 0) { s_v[wave] = bestv; s_i[wave] = besti; }
            __syncthreads();
            if (tid == 0) {
                float fv = s_v[0]; int fi = s_i[0];
                #pragma unroll
                for (int w = 1; w < 4; ++w) {
                    float ov = s_v[w]; int oi = s_i[w];
                    if (ov > fv || (ov == fv && oi < fi)) { fv = ov; fi = oi; }
                }
                l_ub[m] = fv; l_cd[m] = fv; l_ui[m] = fi;
                atomicMax(&win[r * NB + b], packvi(fv, fi));
            }
            __syncthreads();
        }
    }

    grid.sync();                                      // slot 9 final
    if (q == 0 && tid == 0) {
        out[b * NPOINT + 0] = 0;
        #pragma unroll
        for (int r = 1; r < NPOINT; ++r)
            out[b * NPOINT + r] =
                unpack_idx(atomicMax(&win[r * NB + b], 0ULL));
    }
}

extern "C" void kernel_launch(void* const* d_in, const int* in_sizes, int n_in,
                              void* d_out, int out_size, void* d_ws, size_t ws_size,
                              hipStream_t stream) {
    const float* xyz = (const float*)d_in[0];
    int* out = (int*)d_out;
    char* ws = (char*)d_ws;

    float* ub   = (float*)(ws + 0);        // 16 KB
    int*   uidx = (int*)  (ws + 16384);    // 16 KB
    unsigned long long* win = (unsigned long long*)(ws + 32768); // 5120 B

    hipMemsetAsync(win, 0, NPOINT * NB * sizeof(unsigned long long), stream);

    fps_scan1<<<dim3(G, NB), dim3(TPB), 0, stream>>>(xyz, ub, uidx);

    void* args[] = {(void*)&xyz, (void*)&out, (void*)&ub, (void*)&uidx,
                    (void*)&win};
    hipLaunchCooperativeKernel((void*)fps_steps, dim3(NB * BPB), dim3(TPB),
                               args, 0, stream);
}

// Round 8
// 488.588 us; speedup vs baseline: 2.1876x; 2.1876x over previous
//
#include <hip/hip_runtime.h>

// FPS, single cooperative kernel. B=64, N=262144, NPOINT=10.
// Dense pass (vs point 0) -> fine per-chunk UBs (G=256 chunks x 1024 pts).
// Steps 2..9: per-batch spin barrier (8 blocks), cand-refresh (1 dist/chunk)
// -> LB via 128B-padded per-(step,batch) winner slot, wave-granularity exact
// rescans of survivors (staleUB >= LB, strict <). Winner = packed
// (valbits<<32)|(~idx): max val, lowest idx, order-independent.
// R7 bugfix: __syncthreads() BEFORE every barrier arrival — previously tid0
// could arrive while waves 1..3 were still posting scan results, letting
// sibling blocks read an incomplete winner slot.

#define NPOINT 10
#define NB     64
#define NPTS   262144
#define G      256
#define CH     (NPTS / G)     // 1024 pts per chunk
#define TPB    256
#define BPB    8              // blocks per batch
#define CPB    32             // chunks per block
#define WPB    4              // waves per block
#define CPW    8              // chunks per wave
#define LPT    (CH / 64)      // 16 pts per lane per chunk scan
#define INIT_DIST 1e10f

// Strict IEEE, reference association order ((dx^2+dy^2)+dz^2), no contraction.
__device__ __forceinline__ float sqdist(float x, float y, float z,
                                        float cx, float cy, float cz) {
    float dx = x - cx, dy = y - cy, dz = z - cz;
    return __fadd_rn(__fadd_rn(__fmul_rn(dx, dx), __fmul_rn(dy, dy)),
                     __fmul_rn(dz, dz));
}

__device__ __forceinline__ unsigned long long packvi(float v, int i) {
    return ((unsigned long long)__float_as_uint(v) << 32) |
           (unsigned)(0xFFFFFFFFu - (unsigned)i);
}
__device__ __forceinline__ int unpack_idx(unsigned long long w) {
    return (int)(0xFFFFFFFFu - (unsigned)(w & 0xFFFFFFFFull));
}

// Wave-level exact scan of chunk c vs centers 0..R-1; result in lane 0.
template <int R>
__device__ __forceinline__ void scanw(const float* __restrict__ xyzb, int c,
                                      int lane, const float* scx,
                                      const float* scy, const float* scz,
                                      float& outv, int& outi) {
    float cx[R], cy[R], cz[R];
    #pragma unroll
    for (int k = 0; k < R; ++k) { cx[k] = scx[k]; cy[k] = scy[k]; cz[k] = scz[k]; }
    float bestv = -1.0f; int besti = 0;
    const int p0 = c * CH + lane * LPT;
    #pragma unroll
    for (int grp = 0; grp < LPT / 4; ++grp) {
        const float4* src = (const float4*)(xyzb + (size_t)(p0 + grp * 4) * 3);
        float4 a = src[0], c4 = src[1], e = src[2];
        float px[4] = {a.x, a.w, c4.z, e.y};
        float py[4] = {a.y, c4.x, c4.w, e.z};
        float pz[4] = {a.z, c4.y, e.x, e.w};
        #pragma unroll
        for (int j = 0; j < 4; ++j) {
            float dmin = INIT_DIST;
            #pragma unroll
            for (int k = 0; k < R; ++k)
                dmin = fminf(dmin, sqdist(px[j], py[j], pz[j], cx[k], cy[k], cz[k]));
            if (dmin > bestv) { bestv = dmin; besti = p0 + grp * 4 + j; }
        }
    }
    #pragma unroll
    for (int off = 32; off > 0; off >>= 1) {
        float ov = __shfl_down(bestv, off); int oi = __shfl_down(besti, off);
        if (ov > bestv || (ov == bestv && oi < besti)) { bestv = ov; besti = oi; }
    }
    outv = bestv; outi = besti;
}

__global__ __launch_bounds__(TPB, 2) void fps_all(
    const float* __restrict__ xyz, int* __restrict__ out,
    unsigned long long* __restrict__ win,  // (NPOINT*NB) slots, stride 16 u64
    unsigned* __restrict__ bar)            // NB counters, stride 32 u32
{
    const int blk = blockIdx.x;
    const int b = blk / BPB, q = blk % BPB;
    const int tid = threadIdx.x;
    const int lane = tid & 63, wv = tid >> 6;
    const float* xyzb = xyz + (size_t)b * NPTS * 3;
    unsigned long long* const wslot0 = win + (size_t)b * 16;  // + r*NB*16
    unsigned* const cnt = bar + b * 32;

    __shared__ float scx[NPOINT], scy[NPOINT], scz[NPOINT];
    __shared__ float l_ub[CPB], l_cd[CPB];
    __shared__ int   l_ui[CPB];
    __shared__ float s_wv[WPB]; __shared__ int s_wi[WPB];
    __shared__ float s_lb;

    // ---- dense pass: R=1 vs point 0; fills this block's 32 chunk records
    const float c0x = xyzb[0], c0y = xyzb[1], c0z = xyzb[2];
    if (tid == 0) { scx[0] = c0x; scy[0] = c0y; scz[0] = c0z; }
    float wbv = -1.0f; int wbi = 0x7fffffff;
    for (int t = 0; t < CPW; ++t) {
        const int lc = wv * CPW + t;
        const int c  = q * CPB + lc;
        float v; int i;
        const float ax[1] = {c0x}, ay[1] = {c0y}, az[1] = {c0z};
        scanw<1>(xyzb, c, lane, ax, ay, az, v, i);
        if (lane == 0) {
            l_ub[lc] = v; l_cd[lc] = v; l_ui[lc] = i;
            if (v > wbv || (v == wbv && i < wbi)) { wbv = v; wbi = i; }
        }
    }
    if (lane == 0) { s_wv[wv] = wbv; s_wi[wv] = wbi; }
    __syncthreads();
    if (tid == 0) {
        float v = s_wv[0]; int i = s_wi[0];
        #pragma unroll
        for (int w = 1; w < WPB; ++w) {
            float ov = s_wv[w]; int oi = s_wi[w];
            if (ov > v || (ov == v && oi < i)) { v = ov; i = oi; }
        }
        atomicMax(wslot0 + (size_t)1 * NB * 16, packvi(v, i));
    }

    // ---- steps 2..9
    int gen = 0;
    for (int r = 2; r < NPOINT; ++r) {
        ++gen;
        __syncthreads();   // R7 fix: ALL waves' posts drained before arrival
        if (tid == 0) {
            __threadfence();
            atomicAdd(cnt, 1u);
            const unsigned tgt = (unsigned)(gen * BPB);
            while (atomicAdd(cnt, 0u) < tgt) __builtin_amdgcn_s_sleep(2);
            __threadfence();
            // resolve winner of step r-1 -> center r-1
            unsigned long long w = atomicMax(wslot0 + (size_t)(r - 1) * NB * 16, 0ULL);
            int pi = unpack_idx(w);
            const float* pp = xyzb + (size_t)pi * 3;
            scx[r - 1] = pp[0]; scy[r - 1] = pp[1]; scz[r - 1] = pp[2];
        }
        __syncthreads();
        const float pcx = scx[r - 1], pcy = scy[r - 1], pcz = scz[r - 1];

        // cand refresh: exact min-dist of each chunk's last argmax point
        float rv = -1.0f; int ri = 0x7fffffff;
        if (lane < CPW) {
            const int lc = wv * CPW + lane;
            int pi = l_ui[lc];
            const float* pp = xyzb + (size_t)pi * 3;
            float cd = fminf(l_cd[lc], sqdist(pp[0], pp[1], pp[2], pcx, pcy, pcz));
            l_cd[lc] = cd; rv = cd; ri = pi;
        }
        #pragma unroll
        for (int off = 32; off > 0; off >>= 1) {
            float ov = __shfl_down(rv, off); int oi = __shfl_down(ri, off);
            if (ov > rv || (ov == rv && oi < ri)) { rv = ov; ri = oi; }
        }
        if (lane == 0) { s_wv[wv] = rv; s_wi[wv] = ri; }
        __syncthreads();
        unsigned long long* const wr = wslot0 + (size_t)r * NB * 16;
        if (tid == 0) {
            float v = s_wv[0]; int i = s_wi[0];
            #pragma unroll
            for (int w = 1; w < WPB; ++w) {
                float ov = s_wv[w]; int oi = s_wi[w];
                if (ov > v || (ov == v && oi < i)) { v = ov; i = oi; }
            }
            atomicMax(wr, packvi(v, i));
            unsigned long long w = atomicMax(wr, 0ULL);   // LB >= own cands
            s_lb = __uint_as_float((unsigned)(w >> 32));
        }
        __syncthreads();
        const float lbv = s_lb;

        // wave-granularity rescans of surviving chunks
        for (int t = 0; t < CPW; ++t) {
            const int lc = wv * CPW + t;
            if (l_ub[lc] < lbv) continue;        // strict: ties stay scannable
            const int c = q * CPB + lc;
            float v; int i;
            switch (r) {
                case 2: scanw<2>(xyzb, c, lane, scx, scy, scz, v, i); break;
                case 3: scanw<3>(xyzb, c, lane, scx, scy, scz, v, i); break;
                case 4: scanw<4>(xyzb, c, lane, scx, scy, scz, v, i); break;
                case 5: scanw<5>(xyzb, c, lane, scx, scy, scz, v, i); break;
                case 6: scanw<6>(xyzb, c, lane, scx, scy, scz, v, i); break;
                case 7: scanw<7>(xyzb, c, lane, scx, scy, scz, v, i); break;
                case 8: scanw<8>(xyzb, c, lane, scx, scy, scz, v, i); break;
                default: scanw<9>(xyzb, c, lane, scx, scy, scz, v, i); break;
            }
            if (lane == 0) {
                l_ub[lc] = v; l_cd[lc] = v; l_ui[lc] = i;
                atomicMax(wr, packvi(v, i));
            }
        }
    }

    // ---- final barrier + output
    ++gen;
    __syncthreads();       // R7 fix: drain step-9 posts before arrival
    if (tid == 0) {
        __threadfence();
        atomicAdd(cnt, 1u);
        const unsigned tgt = (unsigned)(gen * BPB);
        while (atomicAdd(cnt, 0u) < tgt) __builtin_amdgcn_s_sleep(2);
        __threadfence();
        if (q == 0) {
            out[b * NPOINT + 0] = 0;
            for (int r = 1; r < NPOINT; ++r)
                out[b * NPOINT + r] =
                    unpack_idx(atomicMax(wslot0 + (size_t)r * NB * 16, 0ULL));
        }
    }
}

extern "C" void kernel_launch(void* const* d_in, const int* in_sizes, int n_in,
                              void* d_out, int out_size, void* d_ws, size_t ws_size,
                              hipStream_t stream) {
    const float* xyz = (const float*)d_in[0];
    int* out = (int*)d_out;
    char* ws = (char*)d_ws;

    unsigned long long* win = (unsigned long long*)ws;     // 10*64*16*8 = 81920 B
    unsigned* bar = (unsigned*)(ws + 81920);               // 64*32*4   =  8192 B

    hipMemsetAsync(ws, 0, 81920 + 8192, stream);

    void* args[] = {(void*)&xyz, (void*)&out, (void*)&win, (void*)&bar};
    hipLaunchCooperativeKernel((void*)fps_all, dim3(NB * BPB), dim3(TPB),
                               args, 0, stream);
}